// Round 2
// baseline (349.187 us; speedup 1.0000x reference)
//
#include <hip/hip_runtime.h>

// ConvAttention fused pipeline for MI355X (gfx950), round 2.
//
// Pipeline (5 dispatches):
//  kprep  : fold BN into pointwise weights; Wmix/beta; out_w -> bf16 hi/lo; zero vsum
//  kqkv   : depthwise 3x3 + folded BN + 8x8 pointwise -> q (bf16, pre-scaled), k (bf16), v (f32)
//  kvtrans: v f32 [b,h,n,d] -> vT bf16 [b,h,d,n]  + V row-sum partials (atomicAdd)
//  kattn  : two-pass flash attention; [i][j][c] LDS layout so the cross-head
//           re-attention mix reads one b128 per position; mixed[o][i][j] buffer
//           (XOR-swizzled) feeds PV A-frags; MFMA 16x16x32 bf16
//  kout   : [8192,512]x[512,512]^T projection, bf16 MFMA hi/lo 3-product split

#define EPS 1e-5f
#define SCALE 0.35355339059327373f  // H^-0.5 (reference uses heads for scale)

typedef float f32x4 __attribute__((ext_vector_type(4)));
typedef short short8 __attribute__((ext_vector_type(8)));
typedef unsigned short ushort;

#define MFMA16(a, b, c) __builtin_amdgcn_mfma_f32_16x16x32_bf16(a, b, c, 0, 0, 0)

__device__ __forceinline__ unsigned short f2bf(float f) {
  union { float f; unsigned u; } v; v.f = f;
  return (unsigned short)((v.u + 0x7FFFu + ((v.u >> 16) & 1u)) >> 16);
}
__device__ __forceinline__ float bf2f(unsigned short h) {
  union { unsigned u; float f; } v; v.u = ((unsigned)h) << 16;
  return v.f;
}
__device__ __forceinline__ int cvtpk(float lo, float hi) {
  int r;
  asm("v_cvt_pk_bf16_f32 %0, %1, %2" : "=v"(r) : "v"(lo), "v"(hi));
  return r;  // low 16 = bf16(lo), high 16 = bf16(hi), RNE
}

// ---------------------------------------------------------------- kprep
__global__ __launch_bounds__(256) void kprep(
    const float* __restrict__ dwb, const float* __restrict__ bng,
    const float* __restrict__ bnb, const float* __restrict__ bnm,
    const float* __restrict__ bnv, const float* __restrict__ pww,
    const float* __restrict__ pwb, const float* __restrict__ rew,
    const float* __restrict__ reb, const float* __restrict__ vng,
    const float* __restrict__ vnb, const float* __restrict__ vnm,
    const float* __restrict__ vnv, const float* __restrict__ outw,
    float* __restrict__ smalls, float* __restrict__ vsum,
    ushort* __restrict__ wh, ushort* __restrict__ wl) {
  int g = blockIdx.x * 256 + threadIdx.x;
  if (g < 262144) {
    float v = outw[g];
    ushort hi = f2bf(v);
    wh[g] = hi;
    wl[g] = f2bf(v - bf2f(hi));
  }
  if (blockIdx.x >= 1 && blockIdx.x <= 16)
    vsum[(blockIdx.x - 1) * 256 + threadIdx.x] = 0.f;
  if (blockIdx.x == 0) {
    int t = threadIdx.x;
    if (t < 64) {  // Wmix[o][c] = re_w[o,c] * vn_g[o]/sqrt(vn_v[o]+eps)
      int o = t >> 3, c = t & 7;
      float s = vng[o] * rsqrtf(vnv[o] + EPS);
      smalls[t] = rew[o * 8 + c] * s;
    }
    if (t < 8) {   // beta[o]
      float s = vng[t] * rsqrtf(vnv[t] + EPS);
      smalls[64 + t] = (reb[t] - vnm[t]) * s + vnb[t];
    }
    if (t < 192) { // pw_eff[p][o][c]
      int p = t >> 6, rem = t & 63, o = rem >> 3, c = rem & 7;
      float s = bng[p * 8 + c] * rsqrtf(bnv[p * 8 + c] + EPS);
      smalls[72 + t] = pww[(p * 8 + o) * 8 + c] * s;
    }
    if (t < 24) {  // pwb_eff[p][o]
      int p = t / 8, o = t & 7;
      float acc = pwb[p * 8 + o];
      for (int c = 0; c < 8; ++c) {
        float s = bng[p * 8 + c] * rsqrtf(bnv[p * 8 + c] + EPS);
        acc += pww[(p * 8 + o) * 8 + c] *
               ((dwb[p * 8 + c] - bnm[p * 8 + c]) * s + bnb[p * 8 + c]);
      }
      smalls[264 + t] = acc;
    }
  }
}

// ---------------------------------------------------------------- kqkv
__global__ __launch_bounds__(256) void kqkv(
    const float* __restrict__ x, const float* __restrict__ dww,
    const float* __restrict__ smalls,
    ushort* __restrict__ qb, ushort* __restrict__ kb,
    float* __restrict__ vf) {
  int t = threadIdx.x;
  int blk = blockIdx.x;
  int b = blk >> 8;
  int n0 = (blk & 255) << 2;
  int d = t & 63;
  int n = n0 + (t >> 6);
  const float* pw_eff = smalls + 72;
  const float* pwb_eff = smalls + 264;
  float y[3][8];
  for (int h = 0; h < 8; ++h) {
    float nb[3][3];
#pragma unroll
    for (int ky = 0; ky < 3; ++ky) {
      int nn = n - 1 + ky;
      bool vr = (nn >= 0) && (nn < 1024);
      const float* xp = x + ((b * 1024 + nn) * 512 + h * 64 + d);
      nb[ky][0] = (vr && d > 0) ? xp[-1] : 0.f;
      nb[ky][1] = vr ? xp[0] : 0.f;
      nb[ky][2] = (vr && d < 63) ? xp[1] : 0.f;
    }
#pragma unroll
    for (int p = 0; p < 3; ++p) {
      const float* w = dww + (p * 8 + h) * 9;
      float a = 0.f;
#pragma unroll
      for (int ky = 0; ky < 3; ++ky)
#pragma unroll
        for (int kx = 0; kx < 3; ++kx) a += w[ky * 3 + kx] * nb[ky][kx];
      y[p][h] = a;
    }
  }
#pragma unroll
  for (int p = 0; p < 3; ++p) {
#pragma unroll
    for (int o = 0; o < 8; ++o) {
      float a = pwb_eff[p * 8 + o];
#pragma unroll
      for (int c = 0; c < 8; ++c) a += pw_eff[p * 64 + o * 8 + c] * y[p][c];
      int idx = ((b * 8 + o) * 1024 + n) * 64 + d;
      if (p == 0) qb[idx] = f2bf(a * SCALE);   // fold softmax scale into q
      else if (p == 1) kb[idx] = f2bf(a);
      else vf[idx] = a;
    }
  }
}

// ---------------------------------------------------------------- kvtrans (+vsum)
__global__ __launch_bounds__(256) void kvtrans(const float* __restrict__ vf,
                                               ushort* __restrict__ vt,
                                               float* __restrict__ vsum) {
  __shared__ ushort lds[64 * 65];
  __shared__ float red[256];
  int bh = blockIdx.x >> 4;
  int nt = blockIdx.x & 15;
  int t = threadIdx.x;
  const float* src = vf + (bh * 1024 + nt * 64) * 64;
  float part = 0.f;
#pragma unroll
  for (int it = 0; it < 16; ++it) {
    int nn = (t >> 6) + it * 4;
    int d = t & 63;
    float v = src[nn * 64 + d];
    part += v;
    lds[nn * 65 + d] = f2bf(v);
  }
  red[t] = part;
  __syncthreads();
  ushort* dst = vt + bh * 64 * 1024 + nt * 64;
#pragma unroll
  for (int it = 0; it < 16; ++it) {
    int d = (t >> 6) + it * 4;
    int n = t & 63;
    dst[d * 1024 + n] = lds[n * 65 + d];
  }
  if (t < 64)
    atomicAdd(&vsum[bh * 64 + t],
              red[t] + red[64 + t] + red[128 + t] + red[192 + t]);
}

// ---------------------------------------------------------------- kattn
// Block = (b, 16-row i-tile), 8 waves = 8 heads. Grid 512 (2 blocks/CU).
// LDS: plds [i][j][c] bf16 (16KB), word-swizzled by ((i>>2)&3);
//      mlds [o][i][j] bf16 (16KB), byte-XOR ((i&7))<<4 for conflict-free A reads.
__global__ __launch_bounds__(512, 4) void kattn(
    const ushort* __restrict__ qb, const ushort* __restrict__ kb,
    const ushort* __restrict__ vt, const float* __restrict__ smalls,
    const float* __restrict__ vsum,
    ushort* __restrict__ ohi, ushort* __restrict__ olo) {
  __shared__ ushort plds[16 * 512];
  __shared__ ushort mlds[8 * 1024];
  int b = blockIdx.x & 7;          // bid%8 -> XCD: all i-tiles of one b on one XCD
  int it = blockIdx.x >> 3;
  int i0 = it * 16;
  int tid = threadIdx.x;
  int w = tid >> 6;                // wave id = head
  int l = tid & 63;
  int lrow = l & 15, lgrp = l >> 4;

  const ushort* qh = qb + ((b * 8 + w) * 1024 + i0) * 64;
  const ushort* kh = kb + (b * 8 + w) * 1024 * 64;
  const ushort* vth = vt + (b * 8 + w) * 64 * 1024;

  short8 Qf[2];
#pragma unroll
  for (int kc = 0; kc < 2; ++kc)
    Qf[kc] = *(const short8*)(qh + lrow * 64 + kc * 32 + lgrp * 8);

  // mix geometry: lane owns positions (ip, jp) and (ip, jp+1)
  int ip = w + ((l >> 5) << 3);
  int jp = (l & 31) << 1;
  int s0 = w >> 2;                 // wave-uniform bit of word-perm (folded into W)
  bool s1 = (l >> 5) & 1;          // lane-half bit of word-perm (cndmask)

  // W into SGPRs, pre-permuted by s0: W'[o][c] = W[o][c ^ (s0<<1)]
  float Wc[64];
#pragma unroll
  for (int z = 0; z < 64; ++z) {
    int idx = z ^ (s0 << 1);
    Wc[z] = __builtin_bit_cast(
        float, __builtin_amdgcn_readfirstlane(
                   __builtin_bit_cast(int, smalls[idx])));
  }

  // ---- pass 1: row sums of exp(S)
  float rs[4] = {0.f, 0.f, 0.f, 0.f};
  for (int jt = 0; jt < 16; ++jt) {
    const ushort* kbase = kh + jt * 64 * 64;
    f32x4 acc[4] = {};
#pragma unroll
    for (int q = 0; q < 4; ++q)
#pragma unroll
      for (int kc = 0; kc < 2; ++kc) {
        short8 Kf = *(const short8*)(kbase + (q * 16 + lrow) * 64 + kc * 32 + lgrp * 8);
        acc[q] = MFMA16(Qf[kc], Kf, acc[q]);
      }
#pragma unroll
    for (int q = 0; q < 4; ++q)
#pragma unroll
      for (int r = 0; r < 4; ++r) rs[r] += __expf(acc[q][r]);
  }
#pragma unroll
  for (int r = 0; r < 4; ++r) {
    float v = rs[r];
    v += __shfl_xor(v, 1);
    v += __shfl_xor(v, 2);
    v += __shfl_xor(v, 4);
    v += __shfl_xor(v, 8);
    rs[r] = 1.f / v;
  }

  // ---- pass 2
  f32x4 Oacc[4] = {};
  for (int jt = 0; jt < 16; ++jt) {
    const ushort* kbase = kh + jt * 64 * 64;
    f32x4 acc[4] = {};
#pragma unroll
    for (int q = 0; q < 4; ++q)
#pragma unroll
      for (int kc = 0; kc < 2; ++kc) {
        short8 Kf = *(const short8*)(kbase + (q * 16 + lrow) * 64 + kc * 32 + lgrp * 8);
        acc[q] = MFMA16(Qf[kc], Kf, acc[q]);
      }
    // normalized P -> plds[i][j][c], word-swizzled by (i>>2)&3 (ushort XOR lgrp<<1)
#pragma unroll
    for (int q = 0; q < 4; ++q)
#pragma unroll
      for (int r = 0; r < 4; ++r) {
        float p = __expf(acc[q][r]) * rs[r];
        int pi = (((lgrp * 4 + r) << 9) + ((q * 16 + lrow) << 3) + w) ^ (lgrp << 1);
        plds[pi] = (ushort)cvtpk(p, p);
      }
    __syncthreads();
    // mix: one b128 per position gives all 8 heads
    int pbase = (ip << 9) + (jp << 3);
    int4 r0 = *(const int4*)&plds[pbase];
    int4 r1 = *(const int4*)&plds[pbase + 8];
    int e0[4], e1[4];
    e0[0] = s1 ? r0.z : r0.x;  e0[1] = s1 ? r0.w : r0.y;
    e0[2] = s1 ? r0.x : r0.z;  e0[3] = s1 ? r0.y : r0.w;
    e1[0] = s1 ? r1.z : r1.x;  e1[1] = s1 ? r1.w : r1.y;
    e1[2] = s1 ? r1.x : r1.z;  e1[3] = s1 ? r1.y : r1.w;
    float o0[8] = {}, o1[8] = {};
#pragma unroll
    for (int m = 0; m < 4; ++m) {
      float p0l = __builtin_bit_cast(float, e0[m] << 16);
      float p0h = __builtin_bit_cast(float, (unsigned)e0[m] & 0xffff0000u);
      float p1l = __builtin_bit_cast(float, e1[m] << 16);
      float p1h = __builtin_bit_cast(float, (unsigned)e1[m] & 0xffff0000u);
#pragma unroll
      for (int o = 0; o < 8; ++o) {
        o0[o] += Wc[o * 8 + 2 * m] * p0l + Wc[o * 8 + 2 * m + 1] * p0h;
        o1[o] += Wc[o * 8 + 2 * m] * p1l + Wc[o * 8 + 2 * m + 1] * p1h;
      }
    }
#pragma unroll
    for (int o = 0; o < 8; ++o) {
      int pk = cvtpk(o0[o], o1[o]);
      int mi = ((o << 10) + (ip << 6) + jp) ^ ((ip & 7) << 3);
      *(int*)&mlds[mi] = pk;
    }
    __syncthreads();
    // PV: A-frags from mlds (own head), B-frags from vt
    short8 PA[2];
#pragma unroll
    for (int kc = 0; kc < 2; ++kc) {
      int ai = ((w << 10) + (lrow << 6) + kc * 32 + lgrp * 8) ^ ((lrow & 7) << 3);
      PA[kc] = *(const short8*)&mlds[ai];
    }
#pragma unroll
    for (int nq = 0; nq < 4; ++nq)
#pragma unroll
      for (int kc = 0; kc < 2; ++kc) {
        short8 Vf = *(const short8*)(vth + (nq * 16 + lrow) * 1024 + jt * 64 + kc * 32 + lgrp * 8);
        Oacc[nq] = MFMA16(PA[kc], Vf, Oacc[nq]);
      }
  }

  // ---- epilogue: add exact rank-1 beta*Vsum term, write O hi/lo
  float beta = smalls[64 + w];
#pragma unroll
  for (int nq = 0; nq < 4; ++nq)
#pragma unroll
    for (int r = 0; r < 4; ++r) {
      int i = i0 + lgrp * 4 + r;
      int dd = nq * 16 + lrow;
      float o = Oacc[nq][r] + beta * vsum[(b * 8 + w) * 64 + dd];
      int idx = (b * 1024 + i) * 512 + w * 64 + dd;
      ushort hi = (ushort)cvtpk(o, o);
      ohi[idx] = hi;
      olo[idx] = f2bf(o - bf2f(hi));
    }
}

// ---------------------------------------------------------------- kout
__global__ __launch_bounds__(256) void kout(
    const ushort* __restrict__ ohi, const ushort* __restrict__ olo,
    const ushort* __restrict__ wh, const ushort* __restrict__ wl,
    const float* __restrict__ outb, float* __restrict__ out) {
  int w = threadIdx.x >> 6, l = threadIdx.x & 63;
  int lrow = l & 15, lgrp = l >> 4;
  int i0 = blockIdx.x * 128 + w * 32;
  int n0 = blockIdx.y * 64;
  f32x4 acc[2][4] = {};
  for (int kc = 0; kc < 16; ++kc) {
    short8 Ah[2], Al[2], Bh[4], Bl[4];
#pragma unroll
    for (int a = 0; a < 2; ++a) {
      int ro = (i0 + a * 16 + lrow) * 512 + kc * 32 + lgrp * 8;
      Ah[a] = *(const short8*)(ohi + ro);
      Al[a] = *(const short8*)(olo + ro);
    }
#pragma unroll
    for (int nq = 0; nq < 4; ++nq) {
      int ro = (n0 + nq * 16 + lrow) * 512 + kc * 32 + lgrp * 8;
      Bh[nq] = *(const short8*)(wh + ro);
      Bl[nq] = *(const short8*)(wl + ro);
    }
#pragma unroll
    for (int a = 0; a < 2; ++a)
#pragma unroll
      for (int nq = 0; nq < 4; ++nq) {
        acc[a][nq] = MFMA16(Ah[a], Bh[nq], acc[a][nq]);
        acc[a][nq] = MFMA16(Ah[a], Bl[nq], acc[a][nq]);
        acc[a][nq] = MFMA16(Al[a], Bh[nq], acc[a][nq]);
      }
  }
#pragma unroll
  for (int a = 0; a < 2; ++a)
#pragma unroll
    for (int nq = 0; nq < 4; ++nq)
#pragma unroll
      for (int r = 0; r < 4; ++r) {
        int row = i0 + a * 16 + lgrp * 4 + r;
        int n = n0 + nq * 16 + lrow;
        out[row * 512 + n] = acc[a][nq][r] + outb[n];
      }
}

// ---------------------------------------------------------------- launch
extern "C" void kernel_launch(void* const* d_in, const int* in_sizes, int n_in,
                              void* d_out, int out_size, void* d_ws, size_t ws_size,
                              hipStream_t stream) {
  const float* x   = (const float*)d_in[0];
  const float* dww = (const float*)d_in[1];
  const float* dwb = (const float*)d_in[2];
  const float* bng = (const float*)d_in[3];
  const float* bnb = (const float*)d_in[4];
  const float* bnm = (const float*)d_in[5];
  const float* bnv = (const float*)d_in[6];
  const float* pww = (const float*)d_in[7];
  const float* pwb = (const float*)d_in[8];
  const float* rew = (const float*)d_in[9];
  const float* reb = (const float*)d_in[10];
  const float* vng = (const float*)d_in[11];
  const float* vnb = (const float*)d_in[12];
  const float* vnm = (const float*)d_in[13];
  const float* vnv = (const float*)d_in[14];
  const float* outw = (const float*)d_in[15];
  const float* outb = (const float*)d_in[16];

  char* ws = (char*)d_ws;
  const size_t MB = 1024 * 1024;
  ushort* qb  = (ushort*)(ws);
  ushort* kb  = (ushort*)(ws + 8 * MB);
  ushort* vt  = (ushort*)(ws + 16 * MB);
  float*  vf  = (float*)(ws + 24 * MB);
  ushort* ohi = (ushort*)(ws + 40 * MB);
  ushort* olo = (ushort*)(ws + 48 * MB);
  ushort* wh  = (ushort*)(ws + 56 * MB);
  ushort* wl  = (ushort*)(ws + 56 * MB + 512 * 1024);
  float* smalls = (float*)(ws + 57 * MB);
  float* vsum   = (float*)(ws + 57 * MB + 4096);

  hipLaunchKernelGGL(kprep, dim3(1024), dim3(256), 0, stream,
                     dwb, bng, bnb, bnm, bnv, pww, pwb, rew, reb, vng, vnb,
                     vnm, vnv, outw, smalls, vsum, wh, wl);
  hipLaunchKernelGGL(kqkv, dim3(2048), dim3(256), 0, stream,
                     x, dww, smalls, qb, kb, vf);
  hipLaunchKernelGGL(kvtrans, dim3(1024), dim3(256), 0, stream, vf, vt, vsum);
  hipLaunchKernelGGL(kattn, dim3(512), dim3(512), 0, stream,
                     qb, kb, vt, smalls, vsum, ohi, olo);
  hipLaunchKernelGGL(kout, dim3(64, 8), dim3(256), 0, stream,
                     ohi, olo, wh, wl, outb, (float*)d_out);
}